// Round 8
// baseline (150.011 us; speedup 1.0000x reference)
//
#include <hip/hip_runtime.h>

#define B_ 16
#define C_ 256
#define NH_ 8
#define DK_ 32
#define DV_ 64
#define S_ 1024
#define CV_ 512

typedef __bf16 bf16;
typedef bf16 bf16x4 __attribute__((ext_vector_type(4)));
typedef bf16 bf16x8 __attribute__((ext_vector_type(8)));
typedef float f32x4 __attribute__((ext_vector_type(4)));

constexpr float EPSV = 1e-5f;
constexpr float SCALE_ = 0.17677669529663687f;   // 32^-0.5
constexpr float LOG2E_ = 1.4426950408889634f;
constexpr float QSCALE_ = SCALE_ * LOG2E_;       // folded into Q weights
constexpr float BSCALE_ = (1.0f / SCALE_) * LOG2E_; // folded into bias table

// ---------------- prep: fold BN into weights, cast to bf16; build E4 bias table ----------------
__global__ void prep_kernel(const float* __restrict__ Wq, const float* __restrict__ qg, const float* __restrict__ qb, const float* __restrict__ qm, const float* __restrict__ qv,
                            const float* __restrict__ Wk, const float* __restrict__ kg, const float* __restrict__ kb, const float* __restrict__ km, const float* __restrict__ kv,
                            const float* __restrict__ Wv, const float* __restrict__ vg, const float* __restrict__ vb, const float* __restrict__ vm, const float* __restrict__ vv,
                            const float* __restrict__ Wo, const float* __restrict__ bo, const float* __restrict__ og_, const float* __restrict__ ob_, const float* __restrict__ om_, const float* __restrict__ ov_,
                            const float* __restrict__ pos_emb,
                            bf16* __restrict__ wqkv, float* __restrict__ bqkv, bf16* __restrict__ wo2, float* __restrict__ bo2,
                            f32x4* __restrict__ e4g) {
  int idx = blockIdx.x * 256 + threadIdx.x;
  if (idx < 1024 * 256) {
    int o = idx >> 8, c = idx & 255;
    float w, g, v;
    if (o < 256)      { w = Wq[o * 256 + c];        g = qg[o];       v = qv[o]; }
    else if (o < 512) { w = Wk[(o - 256) * 256 + c]; g = kg[o - 256]; v = kv[o - 256]; }
    else              { w = Wv[(o - 512) * 256 + c]; g = vg[o - 512]; v = vv[o - 512]; }
    float inv = g * rsqrtf(v + EPSV);
    wqkv[idx] = (bf16)(w * inv);
    if (c == 0) {
      float bb, m;
      if (o < 256)      { bb = qb[o];       m = qm[o]; }
      else if (o < 512) { bb = kb[o - 256]; m = km[o - 256]; }
      else              { bb = vb[o - 512]; m = vm[o - 512]; }
      bqkv[o] = bb - m * inv;
    }
  } else if (idx < 1024 * 256 + 256 * 512) {
    int j = idx - 1024 * 256;
    int co = j >> 9, cv = j & 511;
    float inv = og_[co] * rsqrtf(ov_[co] + EPSV);
    wo2[j] = (bf16)(Wo[j] * inv);
    if (cv == 0) bo2[co] = bo[co] * inv + ob_[co] - om_[co] * inv;
  } else {
    // E4 bias quad table: e4g[n][dr][d][j] = pos[(dr*32 + clamp(|d-28-j|))*NH + n] * BSCALE
    int q = idx - (1024 * 256 + 256 * 512);   // 0 .. 16383
    int nn = q >> 11;
    int dr = (q >> 6) & 31;
    int d = q & 63;
    f32x4 v;
#pragma unroll
    for (int j = 0; j < 4; ++j) {
      int dc = d - 28 - j;
      dc = dc < 0 ? -dc : dc;
      dc = dc > 31 ? 31 : dc;
      v[j] = pos_emb[(dr * 32 + dc) * NH_ + nn] * BSCALE_;
    }
    e4g[q] = v;
  }
}

// ---------------- transpose x[b,c,s] f32 -> xT[b,s,c] bf16 ----------------
__global__ __launch_bounds__(256) void xpose_kernel(const float* __restrict__ x, bf16* __restrict__ xT) {
  __shared__ bf16 t[64][66];
  int b = blockIdx.z, c0 = blockIdx.y * 64, s0 = blockIdx.x * 64;
  const float* xp = x + ((size_t)b * C_ + c0) * S_ + s0;
#pragma unroll
  for (int p = 0; p < 16; ++p) {
    int idx = p * 256 + threadIdx.x;
    int ci = idx >> 6, si = idx & 63;
    t[si][ci] = (bf16)xp[(size_t)ci * S_ + si];
  }
  __syncthreads();
  bf16* op = xT + ((size_t)b * S_ + s0) * C_ + c0;
#pragma unroll
  for (int p = 0; p < 16; ++p) {
    int idx = p * 256 + threadIdx.x;
    int si = idx >> 6, ci = idx & 63;
    op[(size_t)si * C_ + ci] = t[si][ci];
  }
}

// ---------------- fused QKV GEMM: C[o,s] = Wqkv[o,:] . xT[b,s,:] + b ----------------
__global__ __launch_bounds__(256) void qkv_gemm_kernel(const bf16* __restrict__ wqkv, const float* __restrict__ bqkv,
                                                       const bf16* __restrict__ xT, bf16* __restrict__ qh,
                                                       bf16* __restrict__ kh, bf16* __restrict__ vT) {
  const int b = blockIdx.z;
  const int ob = blockIdx.y * 128, sb = blockIdx.x * 128;
  const int w = threadIdx.x >> 6, lane = threadIdx.x & 63;
  const int g = lane >> 4, lo = lane & 15;
  const int ow = ob + (w >> 1) * 64, sw = sb + (w & 1) * 64;
  f32x4 acc[4][4] = {};
  const bf16* aB = wqkv + (size_t)(ow + lo) * C_ + 8 * g;
  const bf16* bB = xT + ((size_t)b * S_ + sw + lo) * C_ + 8 * g;
  for (int kc = 0; kc < C_; kc += 32) {
    bf16x8 af[4], bfr[4];
#pragma unroll
    for (int i = 0; i < 4; ++i) af[i] = *(const bf16x8*)(aB + (size_t)i * 16 * C_ + kc);
#pragma unroll
    for (int j = 0; j < 4; ++j) bfr[j] = *(const bf16x8*)(bB + (size_t)j * 16 * C_ + kc);
#pragma unroll
    for (int i = 0; i < 4; ++i)
#pragma unroll
      for (int j = 0; j < 4; ++j)
        acc[i][j] = __builtin_amdgcn_mfma_f32_16x16x32_bf16(af[i], bfr[j], acc[i][j], 0, 0, 0);
  }
#pragma unroll
  for (int i = 0; i < 4; ++i) {
    const int o0 = ow + i * 16 + 4 * g;
    const bool isv = o0 >= 512;
    const bool isq = o0 < 256;
    float bias4[4];
#pragma unroll
    for (int r = 0; r < 4; ++r) bias4[r] = bqkv[o0 + r];
#pragma unroll
    for (int j = 0; j < 4; ++j) {
      const int s = sw + j * 16 + lo;
      if (!isv) {
        const int n = (o0 >> 5) & 7;
        const int d0 = o0 & 31;
        bf16x4 pk;
#pragma unroll
        for (int r = 0; r < 4; ++r) {
          float v = acc[i][j][r] + bias4[r];
          pk[r] = (bf16)(isq ? v * QSCALE_ : v);
        }
        bf16* dst = (isq ? qh : kh) + (((size_t)b * NH_ + n) * S_ + s) * DK_ + d0;
        *(bf16x4*)dst = pk;
      } else {
        const int o2 = o0 - 512;
        const int n = o2 >> 6, dv0 = o2 & 63;
#pragma unroll
        for (int r = 0; r < 4; ++r)
          vT[(((size_t)b * NH_ + n) * DV_ + dv0 + r) * S_ + s] = (bf16)(acc[i][j][r] + bias4[r]);
      }
    }
  }
}

// ---------------- flash attention: 16 q/wave, 1024 blocks (4 blocks/CU, 32 waves/CU) ----------------
// K tile: [64 rows][32 dk] bf16 LDS dbuf, 16B-slot swizzle slot ^= (row>>2)&3.
// V tile: [64 dv ][64 k ] bf16 LDS dbuf, 16B-slot swizzle slot ^= (row&7).
// Both staged via global_load_lds (swizzle on GLOBAL SOURCE, LDS linear, same XOR on read).
// Bias from global E4 quad table (L2-resident, coalesced b128 reads -> mfma C-operand).
// No running max (exp2-domain scores O(+-8)); l via mfma(ones,P).
// Grid (n, qt, b): dispatch_id % 8 == n -> each XCD owns one head's K/V.
__device__ __forceinline__ void gload16(const void* g, void* l) {
  __builtin_amdgcn_global_load_lds((const __attribute__((address_space(1))) void*)g,
                                   (__attribute__((address_space(3))) void*)l, 16, 0, 0);
}

__global__ __launch_bounds__(512, 8) void attn_kernel(const bf16* __restrict__ qh, const bf16* __restrict__ kh,
                                                      const bf16* __restrict__ vT, const f32x4* __restrict__ e4g,
                                                      bf16* __restrict__ og) {
  __shared__ bf16 klds[2][64 * 32];
  __shared__ bf16 vlds[2][64 * 64];
  const int n = blockIdx.x, qt = blockIdx.y, b = blockIdx.z;
  const int w = threadIdx.x >> 6, lane = threadIdx.x & 63;
  const int g = lane >> 4, lo = lane & 15;
  const size_t bn = (size_t)b * NH_ + n;
  const bf16* __restrict__ kbase = kh + bn * (size_t)S_ * DK_;
  const bf16* __restrict__ vbase = vT + bn * (size_t)DV_ * S_;

  // staging: waves 0-3 stage K (16 rows each), all 8 waves stage V (8 rows each)
  const int krow = (w & 3) * 16 + (lane >> 2), kslot = lane & 3;
  const int vrow = w * 8 + (lane >> 3), vslot = lane & 7;
  const bf16* ksrc0 = kbase + (size_t)krow * DK_ + ((kslot ^ ((krow >> 2) & 3)) * 8);
  const bf16* vsrc0 = vbase + (size_t)vrow * S_ + ((vslot ^ (vrow & 7)) * 8);
  auto stage = [&](int buf, int kt) {
    if (w < 4) gload16(ksrc0 + (size_t)kt * DK_, &klds[buf][(w & 3) * 512]);
    gload16(vsrc0 + kt, &vlds[buf][w * 512]);
  };

  stage(0, 0);

  const int qbase = qt * 128 + w * 16;          // 16 q per wave
  const int q0 = qbase + lo;
  const bf16x8 qf = *(const bf16x8*)(qh + (bn * S_ + q0) * DK_ + 8 * g);
  const int qr = qbase >> 5;
  const int qoff = (qbase >> 4) & 1;            // q-half within the 32-row block
  // Ebase: quad index such that Ebase[16] = W0 (even key-half), Ebase[0] = odd key-half
  const f32x4* __restrict__ Ebase = e4g + n * 2048 + (12 + lo - 4 * g + 16 * qoff);

  f32x4 acc[4] = {};
  f32x4 lac = {};
  bf16x8 ones;
#pragma unroll
  for (int j = 0; j < 8; ++j) ones[j] = (bf16)1.0f;

  asm volatile("s_waitcnt vmcnt(0)" ::: "memory");
  __syncthreads();

  for (int it = 0; it < 16; ++it) {
    const int kt = it * 64;
    const int cur = it & 1;
    if (it < 15) stage(cur ^ 1, kt + 64);
    const bf16* kbuf = &klds[cur][0];
    const bf16* vbuf = &vlds[cur][0];

    // ---- bias quads for this tile's two key-rows (global, L2) ----
    int dq = qr - 2 * it;
    int dra = dq < 0 ? -dq : dq;
    int dqb = dq - 1;
    int drb = dqb < 0 ? -dqb : dqb;
    const f32x4* pa = Ebase + dra * 64;
    const f32x4* pq = Ebase + drb * 64;
    f32x4 ca1 = pa[16], ca0 = pa[0], cb1 = pq[16], cb0 = pq[0];

    // ---- QK^T with bias in C-operand; exp2 -> PV B-fragments ----
    bf16x8 pbf[2];  // [key-half]
#pragma unroll
    for (int u = 0; u < 4; ++u) {
      const int row = u * 16 + lo;
      bf16x8 ka = *(const bf16x8*)(kbuf + row * 32 + ((8 * g) ^ (((row >> 2) & 3) << 3)));
      f32x4 cc = (u == 0) ? ca1 : (u == 1) ? ca0 : (u == 2) ? cb1 : cb0;
      f32x4 s0 = __builtin_amdgcn_mfma_f32_16x16x32_bf16(ka, qf, cc, 0, 0, 0);
      const int cb2 = (u & 1) * 4;
      const int up = u >> 1;
#pragma unroll
      for (int r = 0; r < 4; ++r)
        pbf[up][cb2 + r] = (bf16)__builtin_amdgcn_exp2f(s0[r]);
    }

    __builtin_amdgcn_s_setprio(1);
    // ---- row-sum l via ones-MFMA ----
    lac = __builtin_amdgcn_mfma_f32_16x16x32_bf16(ones, pbf[0], lac, 0, 0, 0);
    lac = __builtin_amdgcn_mfma_f32_16x16x32_bf16(ones, pbf[1], lac, 0, 0, 0);

    // ---- PV: acc[t] += V_frag . P ----
#pragma unroll
    for (int t = 0; t < 4; ++t) {
      const int row = t * 16 + lo;
      const int rsw = row & 7;
      const bf16* vrow_p = vbuf + row * 64 + 4 * (g & 1);
      const int ghalf = g >> 1;
#pragma unroll
      for (int up = 0; up < 2; ++up) {
        bf16x4 a0 = *(const bf16x4*)(vrow_p + ((((4 * up + 0) + ghalf) ^ rsw) << 3));
        bf16x4 a1 = *(const bf16x4*)(vrow_p + ((((4 * up + 2) + ghalf) ^ rsw) << 3));
        bf16x8 va = __builtin_shufflevector(a0, a1, 0, 1, 2, 3, 4, 5, 6, 7);
        acc[t] = __builtin_amdgcn_mfma_f32_16x16x32_bf16(va, pbf[up], acc[t], 0, 0, 0);
      }
    }
    __builtin_amdgcn_s_setprio(0);

    asm volatile("s_waitcnt vmcnt(0)" ::: "memory");
    __syncthreads();
  }

  const float rinv = __builtin_amdgcn_rcpf(lac[0]);
  bf16* op = og + ((size_t)b * S_ + q0) * CV_ + n * DV_;
#pragma unroll
  for (int t = 0; t < 4; ++t) {
    bf16x4 pk;
#pragma unroll
    for (int r = 0; r < 4; ++r) {
      float xo = acc[t][r] * rinv;
      pk[r] = (bf16)(0.5f * xo * (1.f + erff(xo * 0.70710678118654752f)));
    }
    *(bf16x4*)(op + t * 16 + 4 * g) = pk;
  }
}

// ---------------- output GEMM: out[b,co,s] = Wo'[co,:] . og[b,s,:] + bo' ----------------
// 512-thr blocks, 8 waves, 32x32 per wave -> 4096 waves (16 waves/CU).
__global__ __launch_bounds__(512, 4) void out_gemm_kernel(const bf16* __restrict__ wo2, const float* __restrict__ bo2,
                                                          const bf16* __restrict__ og, float* __restrict__ out) {
  const int b = blockIdx.z;
  const int cb = blockIdx.y * 64, sb = blockIdx.x * 128;
  const int w = threadIdx.x >> 6, lane = threadIdx.x & 63;
  const int g = lane >> 4, lo = lane & 15;
  const int cw = cb + (w >> 2) * 32, sw = sb + (w & 3) * 32;
  f32x4 acc[2][2] = {};
  const bf16* aB = wo2 + (size_t)(cw + lo) * CV_ + 8 * g;
  const bf16* bB = og + ((size_t)b * S_ + sw + lo) * CV_ + 8 * g;
#pragma unroll 2
  for (int kc = 0; kc < CV_; kc += 32) {
    bf16x8 af[2], bfr[2];
#pragma unroll
    for (int i = 0; i < 2; ++i) af[i] = *(const bf16x8*)(aB + (size_t)i * 16 * CV_ + kc);
#pragma unroll
    for (int j = 0; j < 2; ++j) bfr[j] = *(const bf16x8*)(bB + (size_t)j * 16 * CV_ + kc);
#pragma unroll
    for (int i = 0; i < 2; ++i)
#pragma unroll
      for (int j = 0; j < 2; ++j)
        acc[i][j] = __builtin_amdgcn_mfma_f32_16x16x32_bf16(af[i], bfr[j], acc[i][j], 0, 0, 0);
  }
#pragma unroll
  for (int i = 0; i < 2; ++i) {
    const int c0 = cw + i * 16 + 4 * g;
    float bias4[4];
#pragma unroll
    for (int r = 0; r < 4; ++r) bias4[r] = bo2[c0 + r];
#pragma unroll
    for (int j = 0; j < 2; ++j) {
      const int s = sw + j * 16 + lo;
#pragma unroll
      for (int r = 0; r < 4; ++r)
        out[((size_t)b * C_ + c0 + r) * S_ + s] = acc[i][j][r] + bias4[r];
    }
  }
}

extern "C" void kernel_launch(void* const* d_in, const int* in_sizes, int n_in,
                              void* d_out, int out_size, void* d_ws, size_t ws_size,
                              hipStream_t stream) {
  (void)in_sizes; (void)n_in; (void)out_size; (void)ws_size;
  const float* x   = (const float*)d_in[0];
  const float* Wq  = (const float*)d_in[1];
  const float* qg  = (const float*)d_in[2];
  const float* qb  = (const float*)d_in[3];
  const float* qm  = (const float*)d_in[4];
  const float* qv  = (const float*)d_in[5];
  const float* Wk  = (const float*)d_in[6];
  const float* kg  = (const float*)d_in[7];
  const float* kb  = (const float*)d_in[8];
  const float* km  = (const float*)d_in[9];
  const float* kv  = (const float*)d_in[10];
  const float* Wv  = (const float*)d_in[11];
  const float* vg  = (const float*)d_in[12];
  const float* vb  = (const float*)d_in[13];
  const float* vm  = (const float*)d_in[14];
  const float* vv  = (const float*)d_in[15];
  const float* pos = (const float*)d_in[16];
  const float* Wo  = (const float*)d_in[17];
  const float* bo  = (const float*)d_in[18];
  const float* ogm = (const float*)d_in[19];
  const float* obt = (const float*)d_in[20];
  const float* omn = (const float*)d_in[21];
  const float* ovr = (const float*)d_in[22];
  float* out = (float*)d_out;

  char* ws = (char*)d_ws;
  size_t off = 0;
  auto take = [&](size_t bytes) { char* p = ws + off; off += (bytes + 255) & ~(size_t)255; return p; };
  bf16*  wqkv = (bf16*) take((size_t)1024 * 256 * 2);
  float* bqkv = (float*)take(1024 * 4);
  bf16*  wo2  = (bf16*) take((size_t)256 * 512 * 2);
  float* bo2  = (float*)take(256 * 4);
  f32x4* e4g  = (f32x4*)take((size_t)NH_ * 32 * 64 * 16);
  bf16*  xT   = (bf16*) take((size_t)B_ * S_ * C_ * 2);
  bf16*  qhb  = (bf16*) take((size_t)B_ * NH_ * S_ * DK_ * 2);
  bf16*  khb  = (bf16*) take((size_t)B_ * NH_ * S_ * DK_ * 2);
  bf16*  vTb  = (bf16*) take((size_t)B_ * NH_ * DV_ * S_ * 2);
  bf16*  ogb  = (bf16*) take((size_t)B_ * S_ * CV_ * 2);

  prep_kernel<<<dim3(1600), dim3(256), 0, stream>>>(Wq, qg, qb, qm, qv, Wk, kg, kb, km, kv,
                                                    Wv, vg, vb, vm, vv, Wo, bo, ogm, obt, omn, ovr,
                                                    pos, wqkv, bqkv, wo2, bo2, e4g);
  xpose_kernel<<<dim3(16, 4, 16), dim3(256), 0, stream>>>(x, xT);
  qkv_gemm_kernel<<<dim3(8, 8, 16), dim3(256), 0, stream>>>(wqkv, bqkv, xT, qhb, khb, vTb);
  attn_kernel<<<dim3(8, 8, 16), dim3(512), 0, stream>>>(qhb, khb, vTb, e4g, ogb);
  out_gemm_kernel<<<dim3(8, 4, 16), dim3(512), 0, stream>>>(wo2, bo2, ogb, out);
}